// Round 10
// baseline (2453.785 us; speedup 1.0000x reference)
//
#include <hip/hip_runtime.h>

#define DT 0.042f
constexpr int B = 64, L = 1024, I = 128, H = 512;

// scan decomposition: 64 groups (1 batch each) x 8 column-slices; each of the
// 256 blocks (1/CU) handles TWO group-slices: (gA = blk&31, s = blk>>5) and
// (gB = gA+32, s). The two recurrences are independent: B's compute phase
// hides A's exchange round-trip and vice versa.
constexpr int NS = 8;           // column slices
constexpr int SC = H / NS;      // 64 cols per slice / k per wave-chunk

// ---------------------------------------------------------------------------
// Kernel 1: u = x @ x2h + bias -> staged into the all_states region of d_out
// ---------------------------------------------------------------------------
__global__ __launch_bounds__(256) void k_ugemm(const float* __restrict__ x,
                                               const float* __restrict__ w,
                                               const float* __restrict__ bias,
                                               float* __restrict__ u) {
    __shared__ __align__(16) float a_s[64][132];
    __shared__ __align__(16) float b_s[128][68];
    const int tx = threadIdx.x & 15;
    const int ty = threadIdx.x >> 4;
    const int row0 = blockIdx.x * 64;
    const int col0 = blockIdx.y * 64;

    for (int i = threadIdx.x; i < 64 * 32; i += 256) {
        int r = i >> 5, c4 = (i & 31) << 2;
        *(float4*)&a_s[r][c4] = *(const float4*)(x + (size_t)(row0 + r) * I + c4);
    }
    for (int i = threadIdx.x; i < 128 * 16; i += 256) {
        int k = i >> 4, c4 = (i & 15) << 2;
        *(float4*)&b_s[k][c4] = *(const float4*)(w + (size_t)k * H + col0 + c4);
    }
    __syncthreads();

    float acc[4][4] = {};
    for (int k = 0; k < I; k += 4) {
        float a4[4][4], b4[4][4];
        #pragma unroll
        for (int i = 0; i < 4; ++i) *(float4*)a4[i] = *(const float4*)&a_s[ty * 4 + i][k];
        #pragma unroll
        for (int kk = 0; kk < 4; ++kk) *(float4*)b4[kk] = *(const float4*)&b_s[k + kk][tx * 4];
        #pragma unroll
        for (int i = 0; i < 4; ++i)
            #pragma unroll
            for (int kk = 0; kk < 4; ++kk)
                #pragma unroll
                for (int j = 0; j < 4; ++j)
                    acc[i][j] += a4[i][kk] * b4[kk][j];
    }
    float4 bv = *(const float4*)&bias[col0 + tx * 4];
    #pragma unroll
    for (int i = 0; i < 4; ++i) {
        size_t r = (size_t)(row0 + ty * 4 + i);
        float4 o;
        o.x = acc[i][0] + bv.x; o.y = acc[i][1] + bv.y;
        o.z = acc[i][2] + bv.z; o.w = acc[i][3] + bv.w;
        *(float4*)&u[r * H + col0 + tx * 4] = o;
    }
}

// ---------------------------------------------------------------------------
// Kernel 2: the scan — dual-group interleave, wave-aligned dataflow.
// Per group per step: wave w polls ITS OWN 64 tagged qwords (lane l ->
// hy[g][w*64+l]; hy_s is wave-private: written and read only by wave w ->
// no barrier, no double-buffer, in-order DS pipe) -> matmul (broadcast b128
// reads, hreg operand shared by both groups) -> red write -> barrier ->
// 8 reducer lanes/wave sum 8 partials, update state, publish tag t+1.
// red single-buffer safe: reads of red_X(t) precede the OTHER group's
// barrier; writes of red_X(t+1) follow it. Cross-block reuse safety per
// group as rounds 3-7 (publish t+1 implies all peers consumed t-1).
// Transport: agent-scope relaxed atomics via L3 (the HW-validated path).
// ---------------------------------------------------------------------------
__global__ __launch_bounds__(512, 2) void k_scan(float* __restrict__ su,
                                              const float* __restrict__ h2h,
                                              const float* __restrict__ gamma,
                                              const float* __restrict__ epsv,
                                              unsigned long long* __restrict__ wsq,
                                              float* __restrict__ hyfin) {
    __shared__ __align__(16) float hy_sA[H];      // wave-private slots, 2 KiB
    __shared__ __align__(16) float hy_sB[H];
    __shared__ __align__(16) float redA[H];       // [kc][cc], 2 KiB
    __shared__ __align__(16) float redB[H];
    const int tid = threadIdx.x;
    const int gA = blockIdx.x & 31, gB = gA + 32;
    const int s = blockIdx.x >> 5;
    const int c0 = s * SC;
    const int cc = tid & 63, w = tid >> 6;        // lane, wave(=k-chunk)

    // h2h chunk: hreg[kk] = h2h[w*64+kk][c0+cc] — serves BOTH groups.
    float hreg[64];
    {
        const float* hp = h2h + (size_t)(w * 64) * H + c0 + cc;
        #pragma unroll
        for (int kk = 0; kk < 64; ++kk) hreg[kk] = hp[(size_t)kk * H];
    }

    // reducer role: lanes 0..7 of wave w own cols w*8..w*8+7 of the slice
    const bool isred = (cc < 8);
    const int rc = w * 8 + cc;                    // col within slice
    const int rcg = c0 + rc;                      // global col
    float gam = 0.f, ep = 0.f;
    float *supA = nullptr, *supB = nullptr;
    if (isred) {
        gam = gamma[rcg]; ep = epsv[rcg];
        supA = su + (size_t)gA * L * H + rcg;
        supB = su + (size_t)gB * L * H + rcg;
    }
    unsigned long long* pA0 = wsq + (size_t)gA * H + w * 64 + cc;  // poll, par 0
    unsigned long long* pB0 = wsq + (size_t)gB * H + w * 64 + cc;
    unsigned long long* dA0 = wsq + (size_t)gA * H + rcg;          // publish
    unsigned long long* dB0 = wsq + (size_t)gB * H + rcg;
    const size_t BUF = (size_t)B * H;

    float hyA = 0.f, hzA = 0.f, hyB = 0.f, hzB = 0.f;
    __syncthreads();

    for (int t = 0; t < L; ++t) {
        const unsigned tg = (unsigned)t;
        const size_t po = (t & 1) ? BUF : 0;      // poll parity offset
        const size_t qo = (t & 1) ? 0 : BUF;      // publish parity offset (t+1)

        // ================= group A =================
        float uvA = 0.f;
        if (isred) uvA = *supA;                   // u_A[t] prefetch (under poll)
        if (t > 0) {
            unsigned long long* src = pA0 + po;
            unsigned long long wv = __hip_atomic_load(src, __ATOMIC_RELAXED,
                                                      __HIP_MEMORY_SCOPE_AGENT);
            while ((unsigned)(wv >> 32) != tg)
                wv = __hip_atomic_load(src, __ATOMIC_RELAXED,
                                       __HIP_MEMORY_SCOPE_AGENT);
            hy_sA[w * 64 + cc] = __uint_as_float((unsigned)wv);
        } else {
            hy_sA[w * 64 + cc] = 0.f;
        }
        // wave-private RAW on hy_sA: in-order per-wave DS pipe, no barrier
        float accA = 0.f;
        {
            const float* ha = &hy_sA[w * 64];     // wave-uniform -> broadcast
            #pragma unroll
            for (int q = 0; q < 16; ++q) {
                const float4 y = *(const float4*)(ha + q * 4);
                accA += hreg[q*4+0]*y.x + hreg[q*4+1]*y.y
                      + hreg[q*4+2]*y.z + hreg[q*4+3]*y.w;
            }
        }
        redA[w * 64 + cc] = accA;
        __syncthreads();                          // (A) partials ready
        if (isred) {
            float m = 0.f;
            #pragma unroll
            for (int q = 0; q < 8; ++q) m += redA[q * 64 + rc];
            const float xx = uvA + m;
            const float cx = fminf(fmaxf(xx, -10.f), 10.f);   // tanh via exp
            const float e2 = __expf(2.f * cx);
            const float th = (e2 - 1.f) / (e2 + 1.f);
            hzA += DT * (th - gam * hyA - ep * hzA);
            hyA += DT * hzA;
            const unsigned long long wq =
                ((unsigned long long)(tg + 1) << 32) | __float_as_uint(hyA);
            __hip_atomic_store(dA0 + qo, wq, __ATOMIC_RELAXED,
                               __HIP_MEMORY_SCOPE_AGENT);
            *supA = hyA; supA += H;               // all_states[gA][t][c]
            if (t == L - 1) hyfin[(size_t)gA * H + rcg] = hyA;
        }

        // ================= group B =================
        float uvB = 0.f;
        if (isred) uvB = *supB;                   // u_B[t] prefetch
        if (t > 0) {
            unsigned long long* src = pB0 + po;
            unsigned long long wv = __hip_atomic_load(src, __ATOMIC_RELAXED,
                                                      __HIP_MEMORY_SCOPE_AGENT);
            while ((unsigned)(wv >> 32) != tg)
                wv = __hip_atomic_load(src, __ATOMIC_RELAXED,
                                       __HIP_MEMORY_SCOPE_AGENT);
            hy_sB[w * 64 + cc] = __uint_as_float((unsigned)wv);
        } else {
            hy_sB[w * 64 + cc] = 0.f;
        }
        float accB = 0.f;
        {
            const float* hb = &hy_sB[w * 64];
            #pragma unroll
            for (int q = 0; q < 16; ++q) {
                const float4 y = *(const float4*)(hb + q * 4);
                accB += hreg[q*4+0]*y.x + hreg[q*4+1]*y.y
                      + hreg[q*4+2]*y.z + hreg[q*4+3]*y.w;
            }
        }
        redB[w * 64 + cc] = accB;
        __syncthreads();                          // (B) partials ready
        if (isred) {
            float m = 0.f;
            #pragma unroll
            for (int q = 0; q < 8; ++q) m += redB[q * 64 + rc];
            const float xx = uvB + m;
            const float cx = fminf(fmaxf(xx, -10.f), 10.f);
            const float e2 = __expf(2.f * cx);
            const float th = (e2 - 1.f) / (e2 + 1.f);
            hzB += DT * (th - gam * hyB - ep * hzB);
            hyB += DT * hzB;
            const unsigned long long wq =
                ((unsigned long long)(tg + 1) << 32) | __float_as_uint(hyB);
            __hip_atomic_store(dB0 + qo, wq, __ATOMIC_RELAXED,
                               __HIP_MEMORY_SCOPE_AGENT);
            *supB = hyB; supB += H;               // all_states[gB][t][c]
            if (t == L - 1) hyfin[(size_t)gB * H + rcg] = hyB;
        }
    }
}

extern "C" void kernel_launch(void* const* d_in, const int* in_sizes, int n_in,
                              void* d_out, int out_size, void* d_ws, size_t ws_size,
                              hipStream_t stream) {
    const float* x     = (const float*)d_in[0];
    const float* x2h   = (const float*)d_in[1];
    const float* h2h   = (const float*)d_in[2];
    const float* bias  = (const float*)d_in[3];
    const float* gamma = (const float*)d_in[4];
    const float* epsv  = (const float*)d_in[5];
    float* states = (float*)d_out;                      // (B, L, H)
    float* hyfin  = states + (size_t)B * L * H;         // (B, H)

    unsigned long long* wsq = (unsigned long long*)d_ws;  // 2 x (B*H) tagged qwords

    hipMemsetAsync(d_ws, 0, 2ull * B * H * 8, stream);  // tag 0 != any awaited t>=1
    dim3 g1(B * L / 64, H / 64);
    k_ugemm<<<g1, 256, 0, stream>>>(x, x2h, bias, states);
    k_scan<<<256, 512, 0, stream>>>(states, h2h, gamma, epsv, wsq, hyfin);
}

// Round 11
// 2086.444 us; speedup vs baseline: 1.1761x; 1.1761x over previous
//
#include <hip/hip_runtime.h>

#define DT 0.042f
constexpr int B = 64, L = 1024, I = 128, H = 512;

// scan decomposition: 32 batch-groups x 8 column-slices = 256 blocks (1/CU).
constexpr int NG = 32;          // batch groups
constexpr int NS = 8;           // column slices == k-chunks (1 per wave)
constexpr int GB = B / NG;      // 2 batches per group
constexpr int SC = H / NS;      // 64 cols per slice / k per chunk

// ---------------------------------------------------------------------------
// Kernel 1: u = x @ x2h + bias -> staged into the all_states region of d_out
// ---------------------------------------------------------------------------
__global__ __launch_bounds__(256) void k_ugemm(const float* __restrict__ x,
                                               const float* __restrict__ w,
                                               const float* __restrict__ bias,
                                               float* __restrict__ u) {
    __shared__ __align__(16) float a_s[64][132];
    __shared__ __align__(16) float b_s[128][68];
    const int tx = threadIdx.x & 15;
    const int ty = threadIdx.x >> 4;
    const int row0 = blockIdx.x * 64;
    const int col0 = blockIdx.y * 64;

    for (int i = threadIdx.x; i < 64 * 32; i += 256) {
        int r = i >> 5, c4 = (i & 31) << 2;
        *(float4*)&a_s[r][c4] = *(const float4*)(x + (size_t)(row0 + r) * I + c4);
    }
    for (int i = threadIdx.x; i < 128 * 16; i += 256) {
        int k = i >> 4, c4 = (i & 15) << 2;
        *(float4*)&b_s[k][c4] = *(const float4*)(w + (size_t)k * H + col0 + c4);
    }
    __syncthreads();

    float acc[4][4] = {};
    for (int k = 0; k < I; k += 4) {
        float a4[4][4], b4[4][4];
        #pragma unroll
        for (int i = 0; i < 4; ++i) *(float4*)a4[i] = *(const float4*)&a_s[ty * 4 + i][k];
        #pragma unroll
        for (int kk = 0; kk < 4; ++kk) *(float4*)b4[kk] = *(const float4*)&b_s[k + kk][tx * 4];
        #pragma unroll
        for (int i = 0; i < 4; ++i)
            #pragma unroll
            for (int kk = 0; kk < 4; ++kk)
                #pragma unroll
                for (int j = 0; j < 4; ++j)
                    acc[i][j] += a4[i][kk] * b4[kk][j];
    }
    float4 bv = *(const float4*)&bias[col0 + tx * 4];
    #pragma unroll
    for (int i = 0; i < 4; ++i) {
        size_t r = (size_t)(row0 + ty * 4 + i);
        float4 o;
        o.x = acc[i][0] + bv.x; o.y = acc[i][1] + bv.y;
        o.z = acc[i][2] + bv.z; o.w = acc[i][3] + bv.w;
        *(float4*)&u[r * H + col0 + tx * 4] = o;
    }
}

// ---------------------------------------------------------------------------
// Kernel 2: the scan — R5 protocol with a THINNED intra-block sync graph.
// Wave w == k-chunk w consumes exactly producer slice w's 128 tagged qwords:
// lane l polls hy[b=l>>5][w*64 + 2*(l&31) +{0,1}], writes its float2 into the
// WAVE-PRIVATE hy_s[w] region, and the matmul reads it back via wave-uniform
// ds_read_b128 broadcasts — in-order per-wave DS pipe, so NO barrier(1).
// red is parity-double-buffered, so NO barrier(3): reads of red[t] finish
// before bar(2)@t+1, which precedes any rewrite of red[t] at t+2.
// ONE barrier per step (bar2) keeps the block phase-locked (R4/R10 lesson).
// Cross-block reuse safety: our publish of t+1 follows our bar(2), which
// follows all 8 waves observing tag t from all 8 producers => every producer
// fully consumed t-1; slot (t+1)&1 is dead. Transport: agent-scope relaxed
// atomics via L3 (the HW-validated path).
// ---------------------------------------------------------------------------
__global__ __launch_bounds__(512, 2) void k_scan(float* __restrict__ su,
                                              const float* __restrict__ h2h,
                                              const float* __restrict__ gamma,
                                              const float* __restrict__ epsv,
                                              unsigned long long* __restrict__ wsq,
                                              float* __restrict__ hyfin) {
    __shared__ __align__(16) float hy_s[NS][GB][SC];    // wave-private, 4 KiB
    __shared__ __align__(16) float red[2][NS * GB * SC];// parity bufs,  8 KiB
    const int tid = threadIdx.x;
    const int g = blockIdx.x & 31;    // group (members stride-32 -> same XCD%8)
    const int s = blockIdx.x >> 5;    // column slice 0..7
    const int b0 = g * GB, c0 = s * SC;

    const int cc = tid & 63, w = tid >> 6;        // lane, wave(=k-chunk)
    const int pb = cc >> 5, pk = cc & 31;         // poll role within wave
    const int scc = tid & 63, sb = (tid >> 6) & 1;  // state map (tid < 128)
    const int sc_ = c0 + scc;

    // h2h chunk: hreg[kk] = h2h[w*64+kk][c0+cc] (R5 form, measured-neutral)
    float hreg[64];
    {
        const float* hp = h2h + (size_t)(w * 64) * H + c0 + cc;
        #pragma unroll
        for (int kk = 0; kk < 64; ++kk) hreg[kk] = hp[(size_t)kk * H];
    }

    float gam = 0.f, ep = 0.f;
    float* su_p = nullptr;
    if (tid < 128) {
        gam = gamma[sc_]; ep = epsv[sc_];
        su_p = su + (size_t)(b0 + sb) * L * H + sc_;
    }
    // poll: lane l of wave w owns hy[b=pb][w*64 + 2*pk .. +1] (slice-w data)
    unsigned long long* pollA = wsq + (size_t)(b0 + pb) * H + w * 64 + 2 * pk;
    unsigned long long* pollB = pollA + (size_t)B * H;
    unsigned long long* dstA  = wsq + (size_t)(b0 + sb) * H + sc_;
    unsigned long long* dstB  = dstA + (size_t)B * H;

    float hy = 0.f, hz = 0.f;
    __syncthreads();

    for (int t = 0; t < L; ++t) {
        float uval = 0.f;
        if (tid < 128) uval = *su_p;              // u[t] prefetch, hides under poll

        if (t > 0) {
            unsigned long long* src = (t & 1) ? pollB : pollA;
            unsigned long long w0 = __hip_atomic_load(src + 0, __ATOMIC_RELAXED,
                                                      __HIP_MEMORY_SCOPE_AGENT);
            unsigned long long w1 = __hip_atomic_load(src + 1, __ATOMIC_RELAXED,
                                                      __HIP_MEMORY_SCOPE_AGENT);
            const unsigned tg = (unsigned)t;
            while ((unsigned)(w0 >> 32) != tg || (unsigned)(w1 >> 32) != tg) {
                if ((unsigned)(w0 >> 32) != tg)
                    w0 = __hip_atomic_load(src + 0, __ATOMIC_RELAXED,
                                           __HIP_MEMORY_SCOPE_AGENT);
                if ((unsigned)(w1 >> 32) != tg)
                    w1 = __hip_atomic_load(src + 1, __ATOMIC_RELAXED,
                                           __HIP_MEMORY_SCOPE_AGENT);
            }
            float2 hv;
            hv.x = __uint_as_float((unsigned)w0);
            hv.y = __uint_as_float((unsigned)w1);
            *(float2*)&hy_s[w][pb][2 * pk] = hv;  // wave-private write
        } else {
            *(float2*)&hy_s[w][pb][2 * pk] = float2{0.f, 0.f};
        }
        // NO barrier: hy_s[w] written and read only by wave w (in-order DS pipe)

        // partial matmul: acc[b] = sum_{kk} hreg[kk] * hy_s[w][b][kk]
        float acc0 = 0.f, acc1 = 0.f;
        {
            const float* y0p = &hy_s[w][0][0];    // wave-uniform -> broadcast
            const float* y1p = &hy_s[w][1][0];
            #pragma unroll
            for (int q = 0; q < 16; ++q) {
                const float4 y0 = *(const float4*)(y0p + q * 4);
                const float4 y1 = *(const float4*)(y1p + q * 4);
                acc0 += hreg[q*4+0]*y0.x + hreg[q*4+1]*y0.y
                      + hreg[q*4+2]*y0.z + hreg[q*4+3]*y0.w;
                acc1 += hreg[q*4+0]*y1.x + hreg[q*4+1]*y1.y
                      + hreg[q*4+2]*y1.z + hreg[q*4+3]*y1.w;
            }
        }
        float* rp = red[t & 1];
        rp[w * (GB * SC) + 0 * SC + cc] = acc0;
        rp[w * (GB * SC) + 1 * SC + cc] = acc1;
        __syncthreads();                          // THE phase lock (bar2)

        if (tid < 128) {
            const float* rq = red[t & 1] + sb * SC + scc;
            float m0 = rq[0 * 128] + rq[1 * 128];
            float m1 = rq[2 * 128] + rq[3 * 128];
            float m2 = rq[4 * 128] + rq[5 * 128];
            float m3 = rq[6 * 128] + rq[7 * 128];
            const float xx = uval + ((m0 + m1) + (m2 + m3));
            const float cx = fminf(fmaxf(xx, -10.f), 10.f);  // tanh via exp, clamped
            const float e2 = __expf(2.f * cx);
            const float th = (e2 - 1.f) / (e2 + 1.f);
            hz += DT * (th - gam * hy - ep * hz);
            hy += DT * hz;
            // publish FIRST (critical path), bookkeeping after
            const unsigned long long wq =
                ((unsigned long long)(unsigned)(t + 1) << 32) | __float_as_uint(hy);
            __hip_atomic_store(((t + 1) & 1) ? dstB : dstA, wq,
                               __ATOMIC_RELAXED, __HIP_MEMORY_SCOPE_AGENT);
            *su_p = hy;                           // all_states[b][t][c]
            su_p += H;
            if (t == L - 1) hyfin[(size_t)(b0 + sb) * H + sc_] = hy;
        }
        // NO barrier(3): red parity + wave-private hy_s make it redundant.
    }
}

extern "C" void kernel_launch(void* const* d_in, const int* in_sizes, int n_in,
                              void* d_out, int out_size, void* d_ws, size_t ws_size,
                              hipStream_t stream) {
    const float* x     = (const float*)d_in[0];
    const float* x2h   = (const float*)d_in[1];
    const float* h2h   = (const float*)d_in[2];
    const float* bias  = (const float*)d_in[3];
    const float* gamma = (const float*)d_in[4];
    const float* epsv  = (const float*)d_in[5];
    float* states = (float*)d_out;                      // (B, L, H)
    float* hyfin  = states + (size_t)B * L * H;         // (B, H)

    unsigned long long* wsq = (unsigned long long*)d_ws;  // 2 x (B*H) tagged qwords

    hipMemsetAsync(d_ws, 0, 2ull * B * H * 8, stream);  // tag 0 != any awaited t>=1
    dim3 g1(B * L / 64, H / 64);
    k_ugemm<<<g1, 256, 0, stream>>>(x, x2h, bias, states);
    k_scan<<<NG * NS, 512, 0, stream>>>(states, h2h, gamma, epsv, wsq, hyfin);
}

// Round 12
// 2071.432 us; speedup vs baseline: 1.1846x; 1.0072x over previous
//
#include <hip/hip_runtime.h>

#define DT 0.042f
constexpr int B = 64, L = 1024, I = 128, H = 512;

// scan decomposition: 32 batch-groups x 8 column-slices = 256 blocks (1/CU).
constexpr int NG = 32;          // batch groups
constexpr int NS = 8;           // column slices == k-chunks (1 per wave pair)
constexpr int GB = B / NG;      // 2 batches per group
constexpr int SC = H / NS;      // 64 cols per slice / k per chunk

// ---------------------------------------------------------------------------
// Kernel 1: u = x @ x2h + bias -> staged into the all_states region of d_out
// ---------------------------------------------------------------------------
__global__ __launch_bounds__(256) void k_ugemm(const float* __restrict__ x,
                                               const float* __restrict__ w,
                                               const float* __restrict__ bias,
                                               float* __restrict__ u) {
    __shared__ __align__(16) float a_s[64][132];
    __shared__ __align__(16) float b_s[128][68];
    const int tx = threadIdx.x & 15;
    const int ty = threadIdx.x >> 4;
    const int row0 = blockIdx.x * 64;
    const int col0 = blockIdx.y * 64;

    for (int i = threadIdx.x; i < 64 * 32; i += 256) {
        int r = i >> 5, c4 = (i & 31) << 2;
        *(float4*)&a_s[r][c4] = *(const float4*)(x + (size_t)(row0 + r) * I + c4);
    }
    for (int i = threadIdx.x; i < 128 * 16; i += 256) {
        int k = i >> 4, c4 = (i & 15) << 2;
        *(float4*)&b_s[k][c4] = *(const float4*)(w + (size_t)k * H + col0 + c4);
    }
    __syncthreads();

    float acc[4][4] = {};
    for (int k = 0; k < I; k += 4) {
        float a4[4][4], b4[4][4];
        #pragma unroll
        for (int i = 0; i < 4; ++i) *(float4*)a4[i] = *(const float4*)&a_s[ty * 4 + i][k];
        #pragma unroll
        for (int kk = 0; kk < 4; ++kk) *(float4*)b4[kk] = *(const float4*)&b_s[k + kk][tx * 4];
        #pragma unroll
        for (int i = 0; i < 4; ++i)
            #pragma unroll
            for (int kk = 0; kk < 4; ++kk)
                #pragma unroll
                for (int j = 0; j < 4; ++j)
                    acc[i][j] += a4[i][kk] * b4[kk][j];
    }
    float4 bv = *(const float4*)&bias[col0 + tx * 4];
    #pragma unroll
    for (int i = 0; i < 4; ++i) {
        size_t r = (size_t)(row0 + ty * 4 + i);
        float4 o;
        o.x = acc[i][0] + bv.x; o.y = acc[i][1] + bv.y;
        o.z = acc[i][2] + bv.z; o.w = acc[i][3] + bv.w;
        *(float4*)&u[r * H + col0 + tx * 4] = o;
    }
}

// ---------------------------------------------------------------------------
// Kernel 2: the scan — round-5 skeleton EXACTLY (3 barriers, phase-locked,
// tagged-qword dataflow, 2-qword polls), with ONE change: the h2h slice is
// LDS-RESIDENT instead of re-streamed from L2 every step.
// R5 counters proved hreg never stayed in registers (VGPR=52): each step
// re-read 131 KB/block from L2 (~2340 cy at ~56 B/cy/CU) + 128 VALU
// addr/load instrs per thread. h2hT[k>>2][cc][k&3] gives per-lane contiguous
// 16B reads -> canonical conflict-free ds_read_b128. 136 KiB LDS total.
// ---------------------------------------------------------------------------
__global__ __launch_bounds__(512) void k_scan(float* __restrict__ su,
                                              const float* __restrict__ h2h,
                                              const float* __restrict__ gamma,
                                              const float* __restrict__ epsv,
                                              unsigned long long* __restrict__ wsq,
                                              float* __restrict__ hyfin) {
    __shared__ __align__(16) float h2hT[H / 4 * SC * 4];  // [kg][cc][e] 128 KiB
    __shared__ __align__(16) float hy_s[GB * H];          // [b][k]        4 KiB
    __shared__ __align__(16) float red[NS * GB * SC];     // [kc][b][cc]   4 KiB
    const int tid = threadIdx.x;
    const int g = blockIdx.x & 31;    // group (members stride-32 -> same XCD%8)
    const int s = blockIdx.x >> 5;    // column slice 0..7
    const int b0 = g * GB, c0 = s * SC;

    const int cc = tid & 63, kc = tid >> 6;       // compute map: 64 cols x 8 k-chunks
    const int scc = tid & 63, sb = (tid >> 6) & 1;  // state map (tid < 128)
    const int sc_ = c0 + scc;

    // one-time transposing fill: h2hT[(r>>2)*256 + c*4 + (r&3)] = h2h[r][c0+c]
    for (int i = tid; i < H * SC; i += 512) {
        const int r = i >> 6, c = i & 63;
        h2hT[(r >> 2) * (SC * 4) + c * 4 + (r & 3)] = h2h[(size_t)r * H + c0 + c];
    }

    float gam = 0.f, ep = 0.f;
    float* su_p = nullptr;
    if (tid < 128) {
        gam = gamma[sc_]; ep = epsv[sc_];
        su_p = su + (size_t)(b0 + sb) * L * H + sc_;
    }
    // poll: this thread's 2 qwords of the group's 1024-qword hy region
    unsigned long long* pollA = wsq + (size_t)b0 * H + (size_t)tid * 2;
    unsigned long long* pollB = pollA + (size_t)B * H;
    unsigned long long* dstA  = wsq + (size_t)(b0 + sb) * H + sc_;
    unsigned long long* dstB  = dstA + (size_t)B * H;

    // per-thread h2h base: 16 float4 tiles at stride SC*4 floats
    const float* hv = &h2hT[(kc * 16) * (SC * 4) + cc * 4];

    float hy = 0.f, hz = 0.f;
    __syncthreads();                              // h2hT ready

    for (int t = 0; t < L; ++t) {
        float uval = 0.f;
        if (tid < 128) uval = *su_p;              // u[t] prefetch, hides under poll

        if (t > 0) {
            unsigned long long* src = (t & 1) ? pollB : pollA;
            unsigned long long w0 = __hip_atomic_load(src + 0, __ATOMIC_RELAXED,
                                                      __HIP_MEMORY_SCOPE_AGENT);
            unsigned long long w1 = __hip_atomic_load(src + 1, __ATOMIC_RELAXED,
                                                      __HIP_MEMORY_SCOPE_AGENT);
            const unsigned tg = (unsigned)t;
            while ((unsigned)(w0 >> 32) != tg || (unsigned)(w1 >> 32) != tg) {
                if ((unsigned)(w0 >> 32) != tg)
                    w0 = __hip_atomic_load(src + 0, __ATOMIC_RELAXED,
                                           __HIP_MEMORY_SCOPE_AGENT);
                if ((unsigned)(w1 >> 32) != tg)
                    w1 = __hip_atomic_load(src + 1, __ATOMIC_RELAXED,
                                           __HIP_MEMORY_SCOPE_AGENT);
            }
            float2 hvv;
            hvv.x = __uint_as_float((unsigned)w0);
            hvv.y = __uint_as_float((unsigned)w1);
            *(float2*)&hy_s[tid * 2] = hvv;
        } else {
            *(float2*)&hy_s[tid * 2] = float2{0.f, 0.f};
        }
        __syncthreads();                          // (1) hy_s ready — phase lock

        // partial matmul: acc[b] = sum_{kk} h2hT[kk][cc] * hy[b][kc*64+kk]
        // h2h: 16 private conflict-free b128; hy: 32 wave-uniform broadcasts.
        float acc0 = 0.f, acc1 = 0.f;
        const int k0 = kc * 64;
        #pragma unroll
        for (int q = 0; q < 16; ++q) {
            const float4 hw = *(const float4*)(hv + q * (SC * 4));
            const float4 y0 = *(const float4*)&hy_s[0 * H + k0 + q * 4];
            const float4 y1 = *(const float4*)&hy_s[1 * H + k0 + q * 4];
            acc0 += hw.x * y0.x + hw.y * y0.y + hw.z * y0.z + hw.w * y0.w;
            acc1 += hw.x * y1.x + hw.y * y1.y + hw.z * y1.z + hw.w * y1.w;
        }
        red[kc * (GB * SC) + 0 * SC + cc] = acc0;
        red[kc * (GB * SC) + 1 * SC + cc] = acc1;
        __syncthreads();                          // (2) partials ready

        if (tid < 128) {
            const float* rq = red + sb * SC + scc;
            float m0 = rq[0 * 128] + rq[1 * 128];
            float m1 = rq[2 * 128] + rq[3 * 128];
            float m2 = rq[4 * 128] + rq[5 * 128];
            float m3 = rq[6 * 128] + rq[7 * 128];
            const float xx = uval + ((m0 + m1) + (m2 + m3));
            const float cx = fminf(fmaxf(xx, -10.f), 10.f);  // tanh via exp, clamped
            const float e2 = __expf(2.f * cx);
            const float th = (e2 - 1.f) / (e2 + 1.f);
            hz += DT * (th - gam * hy - ep * hz);
            hy += DT * hz;
            // publish FIRST (critical path), bookkeeping after
            const unsigned long long wq =
                ((unsigned long long)(unsigned)(t + 1) << 32) | __float_as_uint(hy);
            __hip_atomic_store(((t + 1) & 1) ? dstB : dstA, wq,
                               __ATOMIC_RELAXED, __HIP_MEMORY_SCOPE_AGENT);
            *su_p = hy;                           // all_states[b][t][c]
            su_p += H;
            if (t == L - 1) hyfin[(size_t)(b0 + sb) * H + sc_] = hy;
        }
        __syncthreads();                          // (3) red/hy_s safe to overwrite
    }
}

extern "C" void kernel_launch(void* const* d_in, const int* in_sizes, int n_in,
                              void* d_out, int out_size, void* d_ws, size_t ws_size,
                              hipStream_t stream) {
    const float* x     = (const float*)d_in[0];
    const float* x2h   = (const float*)d_in[1];
    const float* h2h   = (const float*)d_in[2];
    const float* bias  = (const float*)d_in[3];
    const float* gamma = (const float*)d_in[4];
    const float* epsv  = (const float*)d_in[5];
    float* states = (float*)d_out;                      // (B, L, H)
    float* hyfin  = states + (size_t)B * L * H;         // (B, H)

    unsigned long long* wsq = (unsigned long long*)d_ws;  // 2 x (B*H) tagged qwords

    hipMemsetAsync(d_ws, 0, 2ull * B * H * 8, stream);  // tag 0 != any awaited t>=1
    dim3 g1(B * L / 64, H / 64);
    k_ugemm<<<g1, 256, 0, stream>>>(x, x2h, bias, states);
    k_scan<<<NG * NS, 512, 0, stream>>>(states, h2h, gamma, epsv, wsq, hyfin);
}